// Round 5
// baseline (1676.096 us; speedup 1.0000x reference)
//
#include <hip/hip_runtime.h>

// VonMisesNet: B=128, V=128, F=40, H=256, L=32, FL=1024, OUT=1
#define Bsz 128
#define Vn  128
#define Fdim 40
#define Hdim 256
#define Lnum 32
#define FLdim 1024
#define LN_EPS 1e-5f

typedef unsigned short u16;
typedef __attribute__((ext_vector_type(8))) short short8;
typedef __attribute__((ext_vector_type(4))) float f32x4;

__device__ __forceinline__ u16 f2bf(float f) {
    unsigned u = __float_as_uint(f);
    u += 0x7fff + ((u >> 16) & 1);          // round-to-nearest-even
    return (u16)(u >> 16);
}
__device__ __forceinline__ float bf2f(u16 s) {
    return __uint_as_float((unsigned)s << 16);
}

// ---------------- rowsum: n[m] = sum_j G[m,j]; invdeg = 1/(n + (n==0)) ----------------
__global__ __launch_bounds__(256) void rowsum_kernel(const float* __restrict__ G,
                                                     float* __restrict__ nrow,
                                                     float* __restrict__ invdeg) {
    int row = blockIdx.x * 4 + (threadIdx.x >> 6);
    int lane = threadIdx.x & 63;
    const float* g = G + (size_t)row * Vn;
    float s = g[lane] + g[lane + 64];
    #pragma unroll
    for (int off = 32; off; off >>= 1) s += __shfl_down(s, off);
    if (lane == 0) {
        nrow[row] = s;
        invdeg[row] = 1.0f / (s + (s == 0.0f ? 1.0f : 0.0f));
    }
}

// ---------------- Gbf[b][i][j] = bf16(G + diag(n)) (exact: 0/1/int) ----------------
__global__ __launch_bounds__(256) void gbf_kernel(const float* __restrict__ G,
                                                  const float* __restrict__ nrow,
                                                  u16* __restrict__ gbf) {
    int gid = blockIdx.x * 256 + threadIdx.x;      // handles 8 j's
    int j8 = gid & 15;
    int m  = gid >> 4;                             // b*128 + i
    int i  = m & 127;
    const float* src = G + (size_t)m * Vn + j8 * 8;
    float4 g0 = *(const float4*)src;
    float4 g1 = *(const float4*)(src + 4);
    float nb = nrow[m];
    float ge[8] = {g0.x, g0.y, g0.z, g0.w, g1.x, g1.y, g1.z, g1.w};
    u16 us[8];
    #pragma unroll
    for (int e = 0; e < 8; ++e) {
        float val = ge[e] + ((j8 * 8 + e) == i ? nb : 0.0f);
        us[e] = f2bf(val);
    }
    uint4 pack;
    pack.x = (unsigned)us[0] | ((unsigned)us[1] << 16);
    pack.y = (unsigned)us[2] | ((unsigned)us[3] << 16);
    pack.z = (unsigned)us[4] | ((unsigned)us[5] << 16);
    pack.w = (unsigned)us[6] | ((unsigned)us[7] << 16);
    *(uint4*)(gbf + (size_t)m * Vn + j8 * 8) = pack;
}

// ------------- transpose+split: src[K][N] f32 -> hi/lo[N][K] bf16 (per blockIdx.z mat) -------------
__global__ __launch_bounds__(256) void tsplit_kernel(const float* __restrict__ src,
                                                     u16* __restrict__ hi, u16* __restrict__ lo,
                                                     int N, int K) {
    __shared__ float tl[64][65];
    size_t mat = (size_t)blockIdx.z * K * N;
    int k0 = blockIdx.x * 64, n0 = blockIdx.y * 64;
    int t = threadIdx.x, c = t & 63, r4 = t >> 6;
    #pragma unroll
    for (int i = 0; i < 16; ++i) {
        int r = i * 4 + r4;
        tl[r][c] = src[mat + (size_t)(k0 + r) * N + n0 + c];
    }
    __syncthreads();
    #pragma unroll
    for (int i = 0; i < 16; ++i) {
        int nr = i * 4 + r4;
        float val = tl[c][nr];
        u16 h = f2bf(val);
        size_t idx = mat + (size_t)(n0 + nr) * K + k0 + c;
        hi[idx] = h;
        lo[idx] = f2bf(val - bf2f(h));
    }
}

// ---------------- feat: v = x@W_feat + b_feat; also write split ----------------
__global__ __launch_bounds__(256) void feat_kernel(const float* __restrict__ x,
                                                   const float* __restrict__ Wf,
                                                   const float* __restrict__ bf,
                                                   float* __restrict__ v,
                                                   u16* __restrict__ vhi,
                                                   u16* __restrict__ vlo) {
    __shared__ float xs[Fdim];
    int row = blockIdx.x;
    int h = threadIdx.x;
    if (h < Fdim) xs[h] = x[(size_t)row * Fdim + h];
    __syncthreads();
    float acc = bf[h];
    #pragma unroll 8
    for (int f = 0; f < Fdim; ++f) acc += xs[f] * Wf[f * Hdim + h];
    size_t idx = (size_t)row * Hdim + h;
    v[idx] = acc;
    u16 hb = f2bf(acc);
    vhi[idx] = hb;
    vlo[idx] = f2bf(acc - bf2f(hb));
}

// ================= fused layer: vp = v@W+b (LDS), m = Gp@vp, v += relu(m/deg) =================
// grid (2 d-halves, 128 batches), 512 threads (8 waves, 2x4 wave grid)
// dynamic LDS 128KB: Gs[128i][128j] | VPH[128d][128j] | VPL | As[128j][64k] | Bs[128d][64k]
// All tiles XOR-swizzled: byte ^ ((row&7)<<4)  (both write & read sides)
__global__ __launch_bounds__(512) void layer_fused(const u16* __restrict__ vhi_in,
                                                   const u16* __restrict__ vlo_in,
                                                   const u16* __restrict__ wthi,
                                                   const u16* __restrict__ wtlo,
                                                   const float* __restrict__ bias,
                                                   const u16* __restrict__ gbf,
                                                   const float* __restrict__ invdeg,
                                                   float* __restrict__ v,
                                                   u16* __restrict__ vhi_out,
                                                   u16* __restrict__ vlo_out) {
    extern __shared__ char smem[];
    char* Gs  = smem;                // 32768 (rows 256B)
    char* VPH = smem + 32768;        // 32768 (rows 256B)
    char* VPL = smem + 65536;        // 32768 (rows 256B)
    char* As  = smem + 98304;        // 16384 (rows 128B)
    char* Bs  = smem + 114688;       // 16384 (rows 128B)

    int tid = threadIdx.x, l = tid & 63, w = tid >> 6;
    int wr = w >> 2, wc = w & 3;     // 2x4 wave grid
    int dh = blockIdx.x;             // d-half (0/1)
    int b  = blockIdx.y;
    const int lr  = l & 15;
    const int lq  = l >> 4;
    const int lkb = lq * 16;
    const int sw  = (lr & 7) << 4;   // per-lane swizzle constant (tile rows ≡ lr mod 8)

    // ---- stage Gs (128x128 bf16 adjacency block), swizzled ----
    const char* gb = (const char*)gbf + (size_t)b * 32768;
    #pragma unroll
    for (int u = 0; u < 4; ++u) {
        int off = (u * 512 + tid) * 16;
        int row = off >> 8;
        *(uint4*)(Gs + (off ^ ((row & 7) << 4))) = *(const uint4*)(gb + off);
    }

    // ---- GEMM1: vp[j][d-cols] = v[b] @ W[:, d-cols], split-bf16 K'=768 ----
    const char* Ain[3] = {(const char*)vhi_in, (const char*)vlo_in, (const char*)vhi_in};
    const char* Bin[3] = {(const char*)wthi, (const char*)wthi, (const char*)wtlo};
    const size_t abase = (size_t)b * 128 * 512;          // v row stride 512B
    const size_t bbase = (size_t)dh * 128 * 512;         // W^T row stride 512B

    f32x4 z = {0.f, 0.f, 0.f, 0.f};
    f32x4 acc[4][2];
    #pragma unroll
    for (int mi = 0; mi < 4; ++mi) { acc[mi][0] = z; acc[mi][1] = z; }

    uint4 pa[2], pb[2];
    auto loadAB = [&](int q) {
        const char* Aseg = Ain[q >> 2] + abase + (q & 3) * 128;
        const char* Bseg = Bin[q >> 2] + bbase + (q & 3) * 128;
        #pragma unroll
        for (int u = 0; u < 2; ++u) {
            int off = (u * 512 + tid) * 16;
            int row = off >> 7;
            pa[u] = *(const uint4*)(Aseg + (size_t)row * 512 + (off & 127));
            pb[u] = *(const uint4*)(Bseg + (size_t)row * 512 + (off & 127));
        }
    };
    loadAB(0);
    for (int q = 0; q < 12; ++q) {
        #pragma unroll
        for (int u = 0; u < 2; ++u) {
            int off = (u * 512 + tid) * 16;
            int row = off >> 7;
            int swo = off ^ ((row & 7) << 4);
            *(uint4*)(As + swo) = pa[u];
            *(uint4*)(Bs + swo) = pb[u];
        }
        __syncthreads();
        if (q < 11) loadAB(q + 1);                 // issue-early: lands under MFMA
        #pragma unroll
        for (int kk = 0; kk < 2; ++kk) {
            short8 a[4], bf8[2];
            #pragma unroll
            for (int mi = 0; mi < 4; ++mi)
                a[mi] = *(const short8*)(As + (((wr * 64 + mi * 16 + lr) * 128 + kk * 64 + lkb) ^ sw));
            #pragma unroll
            for (int ni = 0; ni < 2; ++ni)
                bf8[ni] = *(const short8*)(Bs + (((wc * 32 + ni * 16 + lr) * 128 + kk * 64 + lkb) ^ sw));
            #pragma unroll
            for (int mi = 0; mi < 4; ++mi)
                #pragma unroll
                for (int ni = 0; ni < 2; ++ni)
                    acc[mi][ni] = __builtin_amdgcn_mfma_f32_16x16x32_bf16(a[mi], bf8[ni],
                                                                         acc[mi][ni], 0, 0, 0);
        }
        __syncthreads();
    }

    // ---- epilogue 1: +bias, split, store vp to LDS as [d_local][j] (swizzled) ----
    #pragma unroll
    for (int ni = 0; ni < 2; ++ni) {
        int dl = wc * 32 + ni * 16 + lr;
        float bv = bias[dh * 128 + dl];
        #pragma unroll
        for (int mi = 0; mi < 4; ++mi) {
            int j0 = wr * 64 + mi * 16 + lq * 4;
            ushort4 hv, lv;
            float v0 = acc[mi][ni][0] + bv;
            float v1 = acc[mi][ni][1] + bv;
            float v2 = acc[mi][ni][2] + bv;
            float v3 = acc[mi][ni][3] + bv;
            hv.x = f2bf(v0); lv.x = f2bf(v0 - bf2f(hv.x));
            hv.y = f2bf(v1); lv.y = f2bf(v1 - bf2f(hv.y));
            hv.z = f2bf(v2); lv.z = f2bf(v2 - bf2f(hv.z));
            hv.w = f2bf(v3); lv.w = f2bf(v3 - bf2f(hv.w));
            int off = (dl * 256 + j0 * 2) ^ sw;
            *(ushort4*)(VPH + off) = hv;
            *(ushort4*)(VPL + off) = lv;
        }
    }
    __syncthreads();

    // ---- GEMM2: C2[d][i] = sum_j vp[d][j] * Gp[i][j]  (Gp symmetric; hi then lo) ----
    f32x4 acc2[4][2];
    #pragma unroll
    for (int mi = 0; mi < 4; ++mi) { acc2[mi][0] = z; acc2[mi][1] = z; }

    #pragma unroll
    for (int s = 0; s < 2; ++s) {
        const char* Aseg = s ? VPL : VPH;
        #pragma unroll
        for (int j0b = 0; j0b < 256; j0b += 128) {
            #pragma unroll
            for (int kk = 0; kk < 2; ++kk) {
                short8 a[4], bf8[2];
                #pragma unroll
                for (int mi = 0; mi < 4; ++mi)
                    a[mi] = *(const short8*)(Aseg + (((wr * 64 + mi * 16 + lr) * 256 + j0b + kk * 64 + lkb) ^ sw));
                #pragma unroll
                for (int ni = 0; ni < 2; ++ni)
                    bf8[ni] = *(const short8*)(Gs + (((wc * 32 + ni * 16 + lr) * 256 + j0b + kk * 64 + lkb) ^ sw));
                #pragma unroll
                for (int mi = 0; mi < 4; ++mi)
                    #pragma unroll
                    for (int ni = 0; ni < 2; ++ni)
                        acc2[mi][ni] = __builtin_amdgcn_mfma_f32_16x16x32_bf16(a[mi], bf8[ni],
                                                                              acc2[mi][ni], 0, 0, 0);
            }
        }
    }

    // ---- epilogue 2: v[b][i][d] += relu(C2/deg); write fp32 master + split ----
    #pragma unroll
    for (int ni = 0; ni < 2; ++ni) {
        int i = wc * 32 + ni * 16 + lr;
        int m = b * 128 + i;
        float idg = invdeg[m];
        #pragma unroll
        for (int mi = 0; mi < 4; ++mi) {
            int d = dh * 128 + wr * 64 + mi * 16 + lq * 4;
            float* pv = v + (size_t)m * 256 + d;
            float4 c4 = *(float4*)pv;
            float n0v = c4.x + fmaxf(acc2[mi][ni][0] * idg, 0.0f);
            float n1v = c4.y + fmaxf(acc2[mi][ni][1] * idg, 0.0f);
            float n2v = c4.z + fmaxf(acc2[mi][ni][2] * idg, 0.0f);
            float n3v = c4.w + fmaxf(acc2[mi][ni][3] * idg, 0.0f);
            *(float4*)pv = make_float4(n0v, n1v, n2v, n3v);
            ushort4 hv, lv;
            hv.x = f2bf(n0v); lv.x = f2bf(n0v - bf2f(hv.x));
            hv.y = f2bf(n1v); lv.y = f2bf(n1v - bf2f(hv.y));
            hv.z = f2bf(n2v); lv.z = f2bf(n2v - bf2f(hv.z));
            hv.w = f2bf(n3v); lv.w = f2bf(n3v - bf2f(hv.w));
            *(ushort4*)(vhi_out + (size_t)m * 256 + d) = hv;
            *(ushort4*)(vlo_out + (size_t)m * 256 + d) = lv;
        }
    }
}

// ---------------- LayerNorm: read v fp32, write split h ----------------
__global__ __launch_bounds__(256) void ln_kernel(const float* __restrict__ v,
                                                 const float* __restrict__ g,
                                                 const float* __restrict__ beta,
                                                 u16* __restrict__ hhi,
                                                 u16* __restrict__ hlo) {
    __shared__ float sbuf[4];
    int row = blockIdx.x;
    int t = threadIdx.x;
    float x = v[(size_t)row * Hdim + t];
    float s = x;
    #pragma unroll
    for (int off = 32; off; off >>= 1) s += __shfl_down(s, off);
    int wid = t >> 6, lane = t & 63;
    if (lane == 0) sbuf[wid] = s;
    __syncthreads();
    float mu = (sbuf[0] + sbuf[1] + sbuf[2] + sbuf[3]) * (1.0f / Hdim);
    __syncthreads();
    float d = x - mu;
    float sq = d * d;
    #pragma unroll
    for (int off = 32; off; off >>= 1) sq += __shfl_down(sq, off);
    if (lane == 0) sbuf[wid] = sq;
    __syncthreads();
    float var = (sbuf[0] + sbuf[1] + sbuf[2] + sbuf[3]) * (1.0f / Hdim);
    float h = d * (1.0f / sqrtf(var + LN_EPS)) * g[t] + beta[t];
    size_t idx = (size_t)row * Hdim + t;
    u16 hb = f2bf(h);
    hhi[idx] = hb;
    hlo[idx] = f2bf(h - bf2f(hb));
}

// ---------------- fused final GEMM (MFMA split, swizzled): part[m][nb] ----------------
__global__ __launch_bounds__(256) void gemm_fin_mfma(const u16* __restrict__ hhi,
                                                     const u16* __restrict__ hlo,
                                                     const u16* __restrict__ wfhi,
                                                     const u16* __restrict__ wflo,
                                                     const float* __restrict__ bfin,
                                                     const float* __restrict__ wout,
                                                     float* __restrict__ part) {
    __shared__ char smem[24576];
    char* As = smem;                 // 16384 (rows 128B)
    char* Bs = smem + 16384;         // 8192  (rows 128B)
    int tid = threadIdx.x, l = tid & 63, w = tid >> 6, wr = w >> 1, wc = w & 1;
    int m0 = blockIdx.x * 128, n0 = blockIdx.y * 64;
    const int lr = l & 15, lq = l >> 4, lkb = lq * 16;
    const int sw = (lr & 7) << 4;
    const char* segA[3] = {(const char*)hhi, (const char*)hlo, (const char*)hhi};
    const char* segB[3] = {(const char*)wfhi, (const char*)wfhi, (const char*)wflo};
    f32x4 z = {0.f, 0.f, 0.f, 0.f};
    f32x4 acc[4][2];
    #pragma unroll
    for (int mi = 0; mi < 4; ++mi) { acc[mi][0] = z; acc[mi][1] = z; }

    uint4 pa[4], pb[2];
    auto loadAB = [&](int q) {
        const char* A = segA[q >> 2] + (size_t)m0 * 512 + (q & 3) * 128;
        const char* B = segB[q >> 2] + (size_t)n0 * 512 + (q & 3) * 128;
        #pragma unroll
        for (int u = 0; u < 4; ++u) {
            int off = (u * 256 + tid) * 16;
            int row = off >> 7;
            pa[u] = *(const uint4*)(A + (size_t)row * 512 + (off & 127));
        }
        #pragma unroll
        for (int u = 0; u < 2; ++u) {
            int off = (u * 256 + tid) * 16;
            int row = off >> 7;
            pb[u] = *(const uint4*)(B + (size_t)row * 512 + (off & 127));
        }
    };
    loadAB(0);
    for (int q = 0; q < 12; ++q) {
        #pragma unroll
        for (int u = 0; u < 4; ++u) {
            int off = (u * 256 + tid) * 16;
            int row = off >> 7;
            *(uint4*)(As + (off ^ ((row & 7) << 4))) = pa[u];
        }
        #pragma unroll
        for (int u = 0; u < 2; ++u) {
            int off = (u * 256 + tid) * 16;
            int row = off >> 7;
            *(uint4*)(Bs + (off ^ ((row & 7) << 4))) = pb[u];
        }
        __syncthreads();
        if (q < 11) loadAB(q + 1);
        #pragma unroll
        for (int kk = 0; kk < 2; ++kk) {
            short8 a[4], b2[2];
            #pragma unroll
            for (int mi = 0; mi < 4; ++mi)
                a[mi] = *(const short8*)(As + (((wr * 64 + mi * 16 + lr) * 128 + kk * 64 + lkb) ^ sw));
            #pragma unroll
            for (int ni = 0; ni < 2; ++ni)
                b2[ni] = *(const short8*)(Bs + (((wc * 32 + ni * 16 + lr) * 128 + kk * 64 + lkb) ^ sw));
            #pragma unroll
            for (int mi = 0; mi < 4; ++mi)
                #pragma unroll
                for (int ni = 0; ni < 2; ++ni)
                    acc[mi][ni] = __builtin_amdgcn_mfma_f32_16x16x32_bf16(a[mi], b2[ni],
                                                                         acc[mi][ni], 0, 0, 0);
        }
        __syncthreads();
    }
    float rs[4][4];
    #pragma unroll
    for (int mi = 0; mi < 4; ++mi)
        #pragma unroll
        for (int r = 0; r < 4; ++r) rs[mi][r] = 0.0f;
    #pragma unroll
    for (int ni = 0; ni < 2; ++ni) {
        int n = n0 + wc * 32 + ni * 16 + lr;
        float bv = bfin[n], wo = wout[n];
        #pragma unroll
        for (int mi = 0; mi < 4; ++mi)
            #pragma unroll
            for (int r = 0; r < 4; ++r)
                rs[mi][r] += fmaxf(acc[mi][ni][r] + bv, 0.0f) * wo;
    }
    float* red = (float*)smem;          // [128][33] floats; loop ended with barrier
    #pragma unroll
    for (int mi = 0; mi < 4; ++mi)
        #pragma unroll
        for (int r = 0; r < 4; ++r) {
            int row = wr * 64 + mi * 16 + lq * 4 + r;
            red[row * 33 + wc * 16 + lr] = rs[mi][r];
        }
    __syncthreads();
    if (tid < 128) {
        float s = 0.0f;
        #pragma unroll
        for (int c = 0; c < 32; ++c) s += red[tid * 33 + c];
        part[(size_t)(m0 + tid) * 16 + blockIdx.y] = s;
    }
}

// ---------------- final reduce ----------------
__global__ __launch_bounds__(256) void final_kernel(const float* __restrict__ part,
                                                    const float* __restrict__ bo,
                                                    float* __restrict__ out) {
    int i = blockIdx.x * 256 + threadIdx.x;
    float s = bo[0];
    #pragma unroll
    for (int t = 0; t < 16; ++t) s += part[(size_t)i * 16 + t];
    out[i] = s;
}

extern "C" void kernel_launch(void* const* d_in, const int* in_sizes, int n_in,
                              void* d_out, int out_size, void* d_ws, size_t ws_size,
                              hipStream_t stream) {
    const float* x        = (const float*)d_in[0];
    const float* G        = (const float*)d_in[1];
    const float* W_feat   = (const float*)d_in[2];
    const float* b_feat   = (const float*)d_in[3];
    const float* W_layers = (const float*)d_in[4];
    const float* b_layers = (const float*)d_in[5];
    const float* ln_g     = (const float*)d_in[6];
    const float* ln_b     = (const float*)d_in[7];
    const float* W_fin    = (const float*)d_in[8];
    const float* b_fin    = (const float*)d_in[9];
    const float* W_out    = (const float*)d_in[10];
    const float* b_out    = (const float*)d_in[11];
    float* out = (float*)d_out;

    const int M = Bsz * Vn;                          // 16384
    char* ws = (char*)d_ws;
    float* v      = (float*)ws;                      ws += (size_t)M * Hdim * 4;     // 16 MB
    u16*   vh0    = (u16*)ws;                        ws += (size_t)M * Hdim * 2;     // 8 MB
    u16*   vl0    = (u16*)ws;                        ws += (size_t)M * Hdim * 2;     // 8 MB
    u16*   vh1    = (u16*)ws;                        ws += (size_t)M * Hdim * 2;     // 8 MB
    u16*   vl1    = (u16*)ws;                        ws += (size_t)M * Hdim * 2;     // 8 MB
    u16*   gbf    = (u16*)ws;                        ws += (size_t)Bsz * Vn * Vn * 2;   // 4 MB
    u16*   wthi   = (u16*)ws;                        ws += (size_t)Lnum * Hdim * Hdim * 2; // 4 MB
    u16*   wtlo   = (u16*)ws;                        ws += (size_t)Lnum * Hdim * Hdim * 2; // 4 MB
    u16*   wfhi   = (u16*)ws;                        ws += (size_t)FLdim * Hdim * 2;  // 0.5 MB
    u16*   wflo   = (u16*)ws;                        ws += (size_t)FLdim * Hdim * 2;  // 0.5 MB
    float* nrow   = (float*)ws;                      ws += (size_t)M * 4;
    float* invdeg = (float*)ws;                      ws += (size_t)M * 4;
    float* part   = (float*)ws;                      ws += (size_t)M * 16 * 4;        // 1 MB

    u16* vh[2] = {vh0, vh1};
    u16* vl[2] = {vl0, vl1};

    hipFuncSetAttribute((const void*)layer_fused,
                        hipFuncAttributeMaxDynamicSharedMemorySize, 131072);

    rowsum_kernel<<<M / 4, 256, 0, stream>>>(G, nrow, invdeg);
    gbf_kernel<<<(Bsz * Vn * 16) / 256, 256, 0, stream>>>(G, nrow, gbf);
    tsplit_kernel<<<dim3(4, 4, Lnum), 256, 0, stream>>>(W_layers, wthi, wtlo, Hdim, Hdim);
    tsplit_kernel<<<dim3(4, 16, 1), 256, 0, stream>>>(W_fin, wfhi, wflo, FLdim, Hdim);
    feat_kernel<<<M, 256, 0, stream>>>(x, W_feat, b_feat, v, vh0, vl0);

    for (int l = 0; l < Lnum; ++l) {
        int in = l & 1, o = in ^ 1;
        layer_fused<<<dim3(2, Bsz), 512, 131072, stream>>>(
            vh[in], vl[in],
            wthi + (size_t)l * Hdim * Hdim, wtlo + (size_t)l * Hdim * Hdim,
            b_layers + (size_t)l * Hdim,
            gbf, invdeg, v, vh[o], vl[o]);
    }

    ln_kernel<<<M, 256, 0, stream>>>(v, ln_g, ln_b, vh0, vl0);
    gemm_fin_mfma<<<dim3(M / 128, FLdim / 64), 256, 0, stream>>>(
        vh0, vl0, wfhi, wflo, b_fin, W_out, part);
    final_kernel<<<M / 256, 256, 0, stream>>>(part, b_out, out);
}

// Round 6
// 698.270 us; speedup vs baseline: 2.4004x; 2.4004x over previous
//
#include <hip/hip_runtime.h>

// VonMisesNet: B=128, V=128, F=40, H=256, L=32, FL=1024, OUT=1
#define Bsz 128
#define Vn  128
#define Fdim 40
#define Hdim 256
#define Lnum 32
#define FLdim 1024
#define LN_EPS 1e-5f

typedef unsigned short u16;
typedef __attribute__((ext_vector_type(8))) short short8;
typedef __attribute__((ext_vector_type(4))) float f32x4;

__device__ __forceinline__ u16 f2bf(float f) {
    unsigned u = __float_as_uint(f);
    u += 0x7fff + ((u >> 16) & 1);          // round-to-nearest-even
    return (u16)(u >> 16);
}
__device__ __forceinline__ float bf2f(u16 s) {
    return __uint_as_float((unsigned)s << 16);
}

// split 8 fp32 -> 8 bf16 hi + 8 bf16 lo, packed as uint4 each (fully unrolled -> regs)
__device__ __forceinline__ void splitpack(const float4& x, const float4& y,
                                          uint4& h, uint4& lo) {
    float f[8] = {x.x, x.y, x.z, x.w, y.x, y.y, y.z, y.w};
    u16 hh[8], ll[8];
    #pragma unroll
    for (int e = 0; e < 8; ++e) {
        hh[e] = f2bf(f[e]);
        ll[e] = f2bf(f[e] - bf2f(hh[e]));
    }
    h.x  = (unsigned)hh[0] | ((unsigned)hh[1] << 16);
    h.y  = (unsigned)hh[2] | ((unsigned)hh[3] << 16);
    h.z  = (unsigned)hh[4] | ((unsigned)hh[5] << 16);
    h.w  = (unsigned)hh[6] | ((unsigned)hh[7] << 16);
    lo.x = (unsigned)ll[0] | ((unsigned)ll[1] << 16);
    lo.y = (unsigned)ll[2] | ((unsigned)ll[3] << 16);
    lo.z = (unsigned)ll[4] | ((unsigned)ll[5] << 16);
    lo.w = (unsigned)ll[6] | ((unsigned)ll[7] << 16);
}

// ---------------- rowsum: n[m] = sum_j G[m,j]; invdeg = 1/(n + (n==0)) ----------------
__global__ __launch_bounds__(256) void rowsum_kernel(const float* __restrict__ G,
                                                     float* __restrict__ nrow,
                                                     float* __restrict__ invdeg) {
    int row = blockIdx.x * 4 + (threadIdx.x >> 6);
    int lane = threadIdx.x & 63;
    const float* g = G + (size_t)row * Vn;
    float s = g[lane] + g[lane + 64];
    #pragma unroll
    for (int off = 32; off; off >>= 1) s += __shfl_down(s, off);
    if (lane == 0) {
        nrow[row] = s;
        invdeg[row] = 1.0f / (s + (s == 0.0f ? 1.0f : 0.0f));
    }
}

// ---------------- Gbf[b][i][j] = bf16(G + diag(n)) (exact: 0/1/int) ----------------
__global__ __launch_bounds__(256) void gbf_kernel(const float* __restrict__ G,
                                                  const float* __restrict__ nrow,
                                                  u16* __restrict__ gbf) {
    int gid = blockIdx.x * 256 + threadIdx.x;      // handles 8 j's
    int j8 = gid & 15;
    int m  = gid >> 4;                             // b*128 + i
    int i  = m & 127;
    const float* src = G + (size_t)m * Vn + j8 * 8;
    float4 g0 = *(const float4*)src;
    float4 g1 = *(const float4*)(src + 4);
    float nb = nrow[m];
    float ge[8] = {g0.x, g0.y, g0.z, g0.w, g1.x, g1.y, g1.z, g1.w};
    u16 us[8];
    #pragma unroll
    for (int e = 0; e < 8; ++e) {
        float val = ge[e] + ((j8 * 8 + e) == i ? nb : 0.0f);
        us[e] = f2bf(val);
    }
    uint4 pack;
    pack.x = (unsigned)us[0] | ((unsigned)us[1] << 16);
    pack.y = (unsigned)us[2] | ((unsigned)us[3] << 16);
    pack.z = (unsigned)us[4] | ((unsigned)us[5] << 16);
    pack.w = (unsigned)us[6] | ((unsigned)us[7] << 16);
    *(uint4*)(gbf + (size_t)m * Vn + j8 * 8) = pack;
}

// ------------- transpose+split: src[K][N] f32 -> hi/lo[N][K] bf16 (per blockIdx.z mat) -------------
__global__ __launch_bounds__(256) void tsplit_kernel(const float* __restrict__ src,
                                                     u16* __restrict__ hi, u16* __restrict__ lo,
                                                     int N, int K) {
    __shared__ float tl[64][65];
    size_t mat = (size_t)blockIdx.z * K * N;
    int k0 = blockIdx.x * 64, n0 = blockIdx.y * 64;
    int t = threadIdx.x, c = t & 63, r4 = t >> 6;
    #pragma unroll
    for (int i = 0; i < 16; ++i) {
        int r = i * 4 + r4;
        tl[r][c] = src[mat + (size_t)(k0 + r) * N + n0 + c];
    }
    __syncthreads();
    #pragma unroll
    for (int i = 0; i < 16; ++i) {
        int nr = i * 4 + r4;
        float val = tl[c][nr];
        u16 h = f2bf(val);
        size_t idx = mat + (size_t)(n0 + nr) * K + k0 + c;
        hi[idx] = h;
        lo[idx] = f2bf(val - bf2f(h));
    }
}

// ---------------- feat: v = x@W_feat + b_feat (fp32 master only) ----------------
__global__ __launch_bounds__(256) void feat_kernel(const float* __restrict__ x,
                                                   const float* __restrict__ Wf,
                                                   const float* __restrict__ bf,
                                                   float* __restrict__ v) {
    __shared__ float xs[Fdim];
    int row = blockIdx.x;
    int h = threadIdx.x;
    if (h < Fdim) xs[h] = x[(size_t)row * Fdim + h];
    __syncthreads();
    float acc = bf[h];
    #pragma unroll 8
    for (int f = 0; f < Fdim; ++f) acc += xs[f] * Wf[f * Hdim + h];
    v[(size_t)row * Hdim + h] = acc;
}

// ================= fused layer: vp = v@W+b (LDS), m = Gp@vp, v_out = v_in + relu(m/deg) ======
// grid (2 d-halves, 128 batches), 512 threads (8 waves, 2x4 wave grid)
// LDS 128KB phase1: AsH|AsL|BsH|BsL (4x16K) + VPH|VPL (2x32K); phase2: Gs (32K, aliases AsH/AsL)
// All tiles XOR-swizzled: byte ^ ((row&7)<<4)
__global__ __launch_bounds__(512) void layer_fused(const float* __restrict__ v_in,
                                                   float* __restrict__ v_out,
                                                   const u16* __restrict__ wthi,
                                                   const u16* __restrict__ wtlo,
                                                   const float* __restrict__ bias,
                                                   const u16* __restrict__ gbf,
                                                   const float* __restrict__ invdeg) {
    extern __shared__ char smem[];
    char* AsH = smem;                // 16384 [128j][64k] hi
    char* AsL = smem + 16384;        // 16384 lo
    char* BsH = smem + 32768;        // 16384 [128d][64k] hi
    char* BsL = smem + 49152;        // 16384 lo
    char* VPH = smem + 65536;        // 32768 [128d][128j] hi
    char* VPL = smem + 98304;        // 32768 lo
    char* Gs  = smem;                // 32768 (phase 2; aliases AsH/AsL)

    int tid = threadIdx.x, l = tid & 63, w = tid >> 6;
    int wr = w >> 2, wc = w & 3;     // 2x4 wave grid
    int dh = blockIdx.x;
    int b  = blockIdx.y;
    const int lr  = l & 15;
    const int lq  = l >> 4;
    const int lkb = lq * 16;
    const int sw  = (lr & 7) << 4;

    // ---- prefetch Gs into 4 named regs (parked to LDS after GEMM1) ----
    const char* gb = (const char*)gbf + (size_t)b * 32768;
    uint4 g0 = *(const uint4*)(gb + (size_t)(0 * 512 + tid) * 16);
    uint4 g1 = *(const uint4*)(gb + (size_t)(1 * 512 + tid) * 16);
    uint4 g2 = *(const uint4*)(gb + (size_t)(2 * 512 + tid) * 16);
    uint4 g3 = *(const uint4*)(gb + (size_t)(3 * 512 + tid) * 16);

    // ---- staging geometry (kt-independent) ----
    const float* vb = v_in + (size_t)b * 128 * 256;
    const char* wh = (const char*)wthi + (size_t)dh * 128 * 512;   // [d][k] rows 512B
    const char* wl = (const char*)wtlo + (size_t)dh * 128 * 512;
    const int r0 = tid >> 3,        c0 = (tid & 7) * 8;            // A rows 0..63
    const int r1 = 64 + (tid >> 3), c1 = (tid & 7) * 8;            // A rows 64..127
    const int aoff0 = (r0 * 128 + c0 * 2) ^ ((r0 & 7) << 4);
    const int aoff1 = (r1 * 128 + c1 * 2) ^ ((r1 & 7) << 4);
    // weight chunks: same row/col split (16B bf16 chunks)
    const int wcb0 = (tid & 7) * 16, wcb1 = wcb0;
    const int woff0 = (r0 * 128 + wcb0) ^ ((r0 & 7) << 4);
    const int woff1 = (r1 * 128 + wcb1) ^ ((r1 & 7) << 4);

    float4 a0, a1, a2, a3;
    uint4 bh0, bh1, bl0, bl1;
#define LOADK(kt)                                                                   \
    {                                                                               \
        const float* p0 = vb + (size_t)r0 * 256 + (kt) * 64 + c0;                   \
        const float* p1 = vb + (size_t)r1 * 256 + (kt) * 64 + c1;                   \
        a0 = *(const float4*)p0; a1 = *(const float4*)(p0 + 4);                     \
        a2 = *(const float4*)p1; a3 = *(const float4*)(p1 + 4);                     \
        bh0 = *(const uint4*)(wh + (size_t)r0 * 512 + (kt) * 128 + wcb0);           \
        bh1 = *(const uint4*)(wh + (size_t)r1 * 512 + (kt) * 128 + wcb1);           \
        bl0 = *(const uint4*)(wl + (size_t)r0 * 512 + (kt) * 128 + wcb0);           \
        bl1 = *(const uint4*)(wl + (size_t)r1 * 512 + (kt) * 128 + wcb1);           \
    }

    f32x4 z = {0.f, 0.f, 0.f, 0.f};
    f32x4 acc[4][2];
    #pragma unroll
    for (int mi = 0; mi < 4; ++mi) { acc[mi][0] = z; acc[mi][1] = z; }

#define MMA1(ABUF, BBUF)                                                            \
    {                                                                               \
        _Pragma("unroll")                                                           \
        for (int kk = 0; kk < 2; ++kk) {                                            \
            short8 a[4], bf8[2];                                                    \
            _Pragma("unroll")                                                       \
            for (int mi = 0; mi < 4; ++mi)                                          \
                a[mi] = *(const short8*)((ABUF) + (((wr * 64 + mi * 16 + lr) * 128  \
                             + kk * 64 + lkb) ^ sw));                               \
            _Pragma("unroll")                                                       \
            for (int ni = 0; ni < 2; ++ni)                                          \
                bf8[ni] = *(const short8*)((BBUF) + (((wc * 32 + ni * 16 + lr) * 128\
                             + kk * 64 + lkb) ^ sw));                               \
            _Pragma("unroll")                                                       \
            for (int mi = 0; mi < 4; ++mi)                                          \
                _Pragma("unroll")                                                   \
                for (int ni = 0; ni < 2; ++ni)                                      \
                    acc[mi][ni] = __builtin_amdgcn_mfma_f32_16x16x32_bf16(          \
                        a[mi], bf8[ni], acc[mi][ni], 0, 0, 0);                      \
        }                                                                           \
    }

    LOADK(0);
    for (int kt = 0; kt < 4; ++kt) {
        uint4 ah, alo;
        splitpack(a0, a1, ah, alo);
        *(uint4*)(AsH + aoff0) = ah;  *(uint4*)(AsL + aoff0) = alo;
        splitpack(a2, a3, ah, alo);
        *(uint4*)(AsH + aoff1) = ah;  *(uint4*)(AsL + aoff1) = alo;
        *(uint4*)(BsH + woff0) = bh0; *(uint4*)(BsH + woff1) = bh1;
        *(uint4*)(BsL + woff0) = bl0; *(uint4*)(BsL + woff1) = bl1;
        __syncthreads();
        if (kt < 3) LOADK(kt + 1);          // lands under the 3 MFMA products
        MMA1(AsH, BsH);
        MMA1(AsL, BsH);
        MMA1(AsH, BsL);
        __syncthreads();
    }

    // ---- park Gs (aliases AsH/AsL; all waves are past their As reads) ----
    {
        int i0 = tid, i1 = 512 + tid, i2 = 1024 + tid, i3 = 1536 + tid;
        *(uint4*)(Gs + ((i0 * 16) ^ (((i0 >> 4) & 7) << 4))) = g0;
        *(uint4*)(Gs + ((i1 * 16) ^ (((i1 >> 4) & 7) << 4))) = g1;
        *(uint4*)(Gs + ((i2 * 16) ^ (((i2 >> 4) & 7) << 4))) = g2;
        *(uint4*)(Gs + ((i3 * 16) ^ (((i3 >> 4) & 7) << 4))) = g3;
    }

    // ---- epilogue 1: +bias, split, store vp to LDS as [d_local][j] (swizzled) ----
    #pragma unroll
    for (int ni = 0; ni < 2; ++ni) {
        int dl = wc * 32 + ni * 16 + lr;
        float bv = bias[dh * 128 + dl];
        #pragma unroll
        for (int mi = 0; mi < 4; ++mi) {
            int j0 = wr * 64 + mi * 16 + lq * 4;
            ushort4 hv, lv;
            float v0 = acc[mi][ni][0] + bv;
            float v1 = acc[mi][ni][1] + bv;
            float v2 = acc[mi][ni][2] + bv;
            float v3 = acc[mi][ni][3] + bv;
            hv.x = f2bf(v0); lv.x = f2bf(v0 - bf2f(hv.x));
            hv.y = f2bf(v1); lv.y = f2bf(v1 - bf2f(hv.y));
            hv.z = f2bf(v2); lv.z = f2bf(v2 - bf2f(hv.z));
            hv.w = f2bf(v3); lv.w = f2bf(v3 - bf2f(hv.w));
            int off = (dl * 256 + j0 * 2) ^ sw;
            *(ushort4*)(VPH + off) = hv;
            *(ushort4*)(VPL + off) = lv;
        }
    }
    __syncthreads();

    // ---- GEMM2: C2[d][i] = sum_j vp[d][j] * Gp[i][j]  (hi then lo) ----
    f32x4 acc2[4][2];
    #pragma unroll
    for (int mi = 0; mi < 4; ++mi) { acc2[mi][0] = z; acc2[mi][1] = z; }

    #pragma unroll
    for (int s = 0; s < 2; ++s) {
        const char* Aseg = s ? VPL : VPH;
        #pragma unroll
        for (int j0b = 0; j0b < 256; j0b += 128) {
            #pragma unroll
            for (int kk = 0; kk < 2; ++kk) {
                short8 a[4], bf8[2];
                #pragma unroll
                for (int mi = 0; mi < 4; ++mi)
                    a[mi] = *(const short8*)(Aseg + (((wr * 64 + mi * 16 + lr) * 256 + j0b + kk * 64 + lkb) ^ sw));
                #pragma unroll
                for (int ni = 0; ni < 2; ++ni)
                    bf8[ni] = *(const short8*)(Gs + (((wc * 32 + ni * 16 + lr) * 256 + j0b + kk * 64 + lkb) ^ sw));
                #pragma unroll
                for (int mi = 0; mi < 4; ++mi)
                    #pragma unroll
                    for (int ni = 0; ni < 2; ++ni)
                        acc2[mi][ni] = __builtin_amdgcn_mfma_f32_16x16x32_bf16(a[mi], bf8[ni],
                                                                              acc2[mi][ni], 0, 0, 0);
            }
        }
    }

    // ---- epilogue 2: v_out[b][i][d] = v_in + relu(C2/deg) ----
    #pragma unroll
    for (int ni = 0; ni < 2; ++ni) {
        int i = wc * 32 + ni * 16 + lr;
        int m = b * 128 + i;
        float idg = invdeg[m];
        #pragma unroll
        for (int mi = 0; mi < 4; ++mi) {
            int d = dh * 128 + wr * 64 + mi * 16 + lq * 4;
            float4 c4 = *(const float4*)(v_in + (size_t)m * 256 + d);
            float4 o;
            o.x = c4.x + fmaxf(acc2[mi][ni][0] * idg, 0.0f);
            o.y = c4.y + fmaxf(acc2[mi][ni][1] * idg, 0.0f);
            o.z = c4.z + fmaxf(acc2[mi][ni][2] * idg, 0.0f);
            o.w = c4.w + fmaxf(acc2[mi][ni][3] * idg, 0.0f);
            *(float4*)(v_out + (size_t)m * 256 + d) = o;
        }
    }
#undef LOADK
#undef MMA1
}

// ---------------- LayerNorm: read v fp32, write split h ----------------
__global__ __launch_bounds__(256) void ln_kernel(const float* __restrict__ v,
                                                 const float* __restrict__ g,
                                                 const float* __restrict__ beta,
                                                 u16* __restrict__ hhi,
                                                 u16* __restrict__ hlo) {
    __shared__ float sbuf[4];
    int row = blockIdx.x;
    int t = threadIdx.x;
    float x = v[(size_t)row * Hdim + t];
    float s = x;
    #pragma unroll
    for (int off = 32; off; off >>= 1) s += __shfl_down(s, off);
    int wid = t >> 6, lane = t & 63;
    if (lane == 0) sbuf[wid] = s;
    __syncthreads();
    float mu = (sbuf[0] + sbuf[1] + sbuf[2] + sbuf[3]) * (1.0f / Hdim);
    __syncthreads();
    float d = x - mu;
    float sq = d * d;
    #pragma unroll
    for (int off = 32; off; off >>= 1) sq += __shfl_down(sq, off);
    if (lane == 0) sbuf[wid] = sq;
    __syncthreads();
    float var = (sbuf[0] + sbuf[1] + sbuf[2] + sbuf[3]) * (1.0f / Hdim);
    float h = d * (1.0f / sqrtf(var + LN_EPS)) * g[t] + beta[t];
    size_t idx = (size_t)row * Hdim + t;
    u16 hb = f2bf(h);
    hhi[idx] = hb;
    hlo[idx] = f2bf(h - bf2f(hb));
}

// ---------------- fused final GEMM (direct staging + swizzle): part[m][nb] ----------------
__global__ __launch_bounds__(256) void gemm_fin_mfma(const u16* __restrict__ hhi,
                                                     const u16* __restrict__ hlo,
                                                     const u16* __restrict__ wfhi,
                                                     const u16* __restrict__ wflo,
                                                     const float* __restrict__ bfin,
                                                     const float* __restrict__ wout,
                                                     float* __restrict__ part) {
    __shared__ char smem[24576];
    char* As = smem;                 // 16384 (rows 128B)
    char* Bs = smem + 16384;         // 8192  (rows 128B)
    int tid = threadIdx.x, l = tid & 63, w = tid >> 6, wr = w >> 1, wc = w & 1;
    int m0 = blockIdx.x * 128, n0 = blockIdx.y * 64;
    const int lr = l & 15, lq = l >> 4, lkb = lq * 16;
    const int sw = (lr & 7) << 4;
    const char* segA[3] = {(const char*)hhi, (const char*)hlo, (const char*)hhi};
    const char* segB[3] = {(const char*)wfhi, (const char*)wfhi, (const char*)wflo};
    f32x4 z = {0.f, 0.f, 0.f, 0.f};
    f32x4 acc[4][2];
    #pragma unroll
    for (int mi = 0; mi < 4; ++mi) { acc[mi][0] = z; acc[mi][1] = z; }

    for (int q = 0; q < 12; ++q) {
        const char* A = segA[q >> 2] + (size_t)m0 * 512 + (q & 3) * 128;
        const char* B = segB[q >> 2] + (size_t)n0 * 512 + (q & 3) * 128;
        #pragma unroll
        for (int u = 0; u < 4; ++u) {
            int off = (u * 256 + tid) * 16;
            int row = off >> 7;
            *(uint4*)(As + (off ^ ((row & 7) << 4))) =
                *(const uint4*)(A + (size_t)row * 512 + (off & 127));
        }
        #pragma unroll
        for (int u = 0; u < 2; ++u) {
            int off = (u * 256 + tid) * 16;
            int row = off >> 7;
            *(uint4*)(Bs + (off ^ ((row & 7) << 4))) =
                *(const uint4*)(B + (size_t)row * 512 + (off & 127));
        }
        __syncthreads();
        #pragma unroll
        for (int kk = 0; kk < 2; ++kk) {
            short8 a[4], b2[2];
            #pragma unroll
            for (int mi = 0; mi < 4; ++mi)
                a[mi] = *(const short8*)(As + (((wr * 64 + mi * 16 + lr) * 128 + kk * 64 + lkb) ^ sw));
            #pragma unroll
            for (int ni = 0; ni < 2; ++ni)
                b2[ni] = *(const short8*)(Bs + (((wc * 32 + ni * 16 + lr) * 128 + kk * 64 + lkb) ^ sw));
            #pragma unroll
            for (int mi = 0; mi < 4; ++mi)
                #pragma unroll
                for (int ni = 0; ni < 2; ++ni)
                    acc[mi][ni] = __builtin_amdgcn_mfma_f32_16x16x32_bf16(a[mi], b2[ni],
                                                                         acc[mi][ni], 0, 0, 0);
        }
        __syncthreads();
    }
    float rs[4][4];
    #pragma unroll
    for (int mi = 0; mi < 4; ++mi)
        #pragma unroll
        for (int r = 0; r < 4; ++r) rs[mi][r] = 0.0f;
    #pragma unroll
    for (int ni = 0; ni < 2; ++ni) {
        int n = n0 + wc * 32 + ni * 16 + lr;
        float bv = bfin[n], wo = wout[n];
        #pragma unroll
        for (int mi = 0; mi < 4; ++mi)
            #pragma unroll
            for (int r = 0; r < 4; ++r)
                rs[mi][r] += fmaxf(acc[mi][ni][r] + bv, 0.0f) * wo;
    }
    float* red = (float*)smem;          // [128][33] floats; loop ended with barrier
    #pragma unroll
    for (int mi = 0; mi < 4; ++mi)
        #pragma unroll
        for (int r = 0; r < 4; ++r) {
            int row = wr * 64 + mi * 16 + lq * 4 + r;
            red[row * 33 + wc * 16 + lr] = rs[mi][r];
        }
    __syncthreads();
    if (tid < 128) {
        float s = 0.0f;
        #pragma unroll
        for (int c = 0; c < 32; ++c) s += red[tid * 33 + c];
        part[(size_t)(m0 + tid) * 16 + blockIdx.y] = s;
    }
}

// ---------------- final reduce ----------------
__global__ __launch_bounds__(256) void final_kernel(const float* __restrict__ part,
                                                    const float* __restrict__ bo,
                                                    float* __restrict__ out) {
    int i = blockIdx.x * 256 + threadIdx.x;
    float s = bo[0];
    #pragma unroll
    for (int t = 0; t < 16; ++t) s += part[(size_t)i * 16 + t];
    out[i] = s;
}

extern "C" void kernel_launch(void* const* d_in, const int* in_sizes, int n_in,
                              void* d_out, int out_size, void* d_ws, size_t ws_size,
                              hipStream_t stream) {
    const float* x        = (const float*)d_in[0];
    const float* G        = (const float*)d_in[1];
    const float* W_feat   = (const float*)d_in[2];
    const float* b_feat   = (const float*)d_in[3];
    const float* W_layers = (const float*)d_in[4];
    const float* b_layers = (const float*)d_in[5];
    const float* ln_g     = (const float*)d_in[6];
    const float* ln_b     = (const float*)d_in[7];
    const float* W_fin    = (const float*)d_in[8];
    const float* b_fin    = (const float*)d_in[9];
    const float* W_out    = (const float*)d_in[10];
    const float* b_out    = (const float*)d_in[11];
    float* out = (float*)d_out;

    const int M = Bsz * Vn;                          // 16384
    char* ws = (char*)d_ws;
    float* v0     = (float*)ws;                      ws += (size_t)M * Hdim * 4;     // 16 MB
    float* v1     = (float*)ws;                      ws += (size_t)M * Hdim * 4;     // 16 MB
    u16*   gbf    = (u16*)ws;                        ws += (size_t)Bsz * Vn * Vn * 2;   // 4 MB
    u16*   wthi   = (u16*)ws;                        ws += (size_t)Lnum * Hdim * Hdim * 2; // 4 MB
    u16*   wtlo   = (u16*)ws;                        ws += (size_t)Lnum * Hdim * Hdim * 2; // 4 MB
    u16*   wfhi   = (u16*)ws;                        ws += (size_t)FLdim * Hdim * 2;  // 0.5 MB
    u16*   wflo   = (u16*)ws;                        ws += (size_t)FLdim * Hdim * 2;  // 0.5 MB
    float* nrow   = (float*)ws;                      ws += (size_t)M * 4;
    float* invdeg = (float*)ws;                      ws += (size_t)M * 4;
    float* part   = (float*)ws;                      ws += (size_t)M * 16 * 4;        // 1 MB

    // h splits alias v1 (dead after the layer loop: 32 layers end in v0)
    u16* hh = (u16*)v1;
    u16* hl = hh + (size_t)M * Hdim;

    float* vv[2] = {v0, v1};

    hipFuncSetAttribute((const void*)layer_fused,
                        hipFuncAttributeMaxDynamicSharedMemorySize, 131072);

    rowsum_kernel<<<M / 4, 256, 0, stream>>>(G, nrow, invdeg);
    gbf_kernel<<<(Bsz * Vn * 16) / 256, 256, 0, stream>>>(G, nrow, gbf);
    tsplit_kernel<<<dim3(4, 4, Lnum), 256, 0, stream>>>(W_layers, wthi, wtlo, Hdim, Hdim);
    tsplit_kernel<<<dim3(4, 16, 1), 256, 0, stream>>>(W_fin, wfhi, wflo, FLdim, Hdim);
    feat_kernel<<<M, 256, 0, stream>>>(x, W_feat, b_feat, v0);

    for (int l = 0; l < Lnum; ++l) {
        int in = l & 1;                  // l=0 reads v0 writes v1; alternate
        layer_fused<<<dim3(2, Bsz), 512, 131072, stream>>>(
            vv[in], vv[in ^ 1],
            wthi + (size_t)l * Hdim * Hdim, wtlo + (size_t)l * Hdim * Hdim,
            b_layers + (size_t)l * Hdim,
            gbf, invdeg);
    }

    ln_kernel<<<M, 256, 0, stream>>>(v0, ln_g, ln_b, hh, hl);
    gemm_fin_mfma<<<dim3(M / 128, FLdim / 64), 256, 0, stream>>>(
        hh, hl, wfhi, wflo, b_fin, W_out, part);
    final_kernel<<<M / 256, 256, 0, stream>>>(part, b_out, out);
}